// Round 5
// baseline (191.855 us; speedup 1.0000x reference)
//
#include <hip/hip_runtime.h>
#include <math.h>

// Problem constants (B=4, Nin=64, F=64, T=1024, NH=8, FDIM=64, N=512)
#define QSCALE 0.18033688011112042f   // 0.125 * log2(e): softmax scale folded, exp2 domain

typedef __attribute__((ext_vector_type(4))) float  f32x4;
typedef __attribute__((ext_vector_type(2))) float  f32x2;
typedef __attribute__((ext_vector_type(8))) short  bf16x8;   // MFMA A/B frag (8 bf16)
typedef __attribute__((ext_vector_type(4))) short  bf16x4;   // 8B packed store
typedef __attribute__((ext_vector_type(4))) int    i32x4;    // 16B copy

static __device__ __forceinline__ short f2bf(float f) {
    union { float f; unsigned u; } v; v.f = f;
    unsigned r = v.u + 0x7fffu + ((v.u >> 16) & 1u);   // RNE
    return (short)(r >> 16);
}
static __device__ __forceinline__ int pk2bf(float a, float b) {
    return ((int)f2bf(a) & 0xffff) | ((int)f2bf(b) << 16);
}
static __device__ __forceinline__ float bf2f(short s) {
    union { unsigned u; float f; } v; v.u = ((unsigned)(unsigned short)s) << 16;
    return v.f;
}

#define MFMA16(A,B,C) __builtin_amdgcn_mfma_f32_16x16x32_bf16(A, B, C, 0, 0, 0)

// ---------------------------------------------------------------------------
// Kernel 0: w_qk fp32[1024][512] -> bf16, fold softmax scale*log2e into q-rows
// ---------------------------------------------------------------------------
__global__ void k_prep(const float* __restrict__ wqk, short* __restrict__ wqk_b) {
    int i = blockIdx.x * 256 + threadIdx.x;      // 524288 total
    int D = i >> 9;
    float s = (D & 64) ? 1.0f : QSCALE;
    wqk_b[i] = f2bf(wqk[i] * s);
}

// ---------------------------------------------------------------------------
// Kernel 1: xi[b,h,f,t] = sum_c w_in[h,c] * x[b,c,f,t]
// 2 t per thread, f32x2 loads, depth-8 pipeline.
// Outputs: xi_v[b][h][f][t] bf16; xr_t[b][t][c] bf16 via LDS transpose.
// Grid (16 tb, 8 fb, 4 b) = 512 blocks.
// ---------------------------------------------------------------------------
__global__ __launch_bounds__(256) void k_proj_in(
    const float* __restrict__ x, const float* __restrict__ w_in,
    short* __restrict__ xi_v, short* __restrict__ xr_t)
{
    __shared__ float w_s[512];                    // w_in [8][64]
    __shared__ __align__(16) short tr[64 * 72];   // [t-local][c'=h*8+fy], pad 72
    int tid = threadIdx.x;
    int tx = tid & 31, fy = tid >> 5;
    int tb = blockIdx.x, fb = blockIdx.y, b = blockIdx.z;
    w_s[tid] = w_in[tid & 511];
    w_s[(tid + 256) & 511] = w_in[(tid + 256) & 511];
    __syncthreads();

    int f = fb * 8 + fy;
    int t = tb * 64 + tx * 2;
    float acc[8][2];
    #pragma unroll
    for (int h = 0; h < 8; h++) { acc[h][0] = 0.f; acc[h][1] = 0.f; }

    const float* xp = x + ((size_t)b * 64 * 64 + (size_t)f) * 1024 + t;
    f32x2 buf[8];
    #pragma unroll
    for (int i = 0; i < 8; i++) buf[i] = *(const f32x2*)&xp[(size_t)i * 65536];
    #pragma unroll
    for (int c8 = 0; c8 < 64; c8 += 8) {
        f32x2 cur[8];
        #pragma unroll
        for (int i = 0; i < 8; i++) cur[i] = buf[i];
        if (c8 + 8 < 64) {
            #pragma unroll
            for (int i = 0; i < 8; i++)
                buf[i] = *(const f32x2*)&xp[(size_t)(c8 + 8 + i) * 65536];
        }
        #pragma unroll
        for (int i = 0; i < 8; i++)
            #pragma unroll
            for (int h = 0; h < 8; h++) {
                float wv = w_s[h * 64 + c8 + i];
                acc[h][0] = fmaf(cur[i][0], wv, acc[h][0]);
                acc[h][1] = fmaf(cur[i][1], wv, acc[h][1]);
            }
    }
    // xi_v[b][h][f][t..t+1] (4B packed store)
    #pragma unroll
    for (int h = 0; h < 8; h++)
        *(int*)&xi_v[(((size_t)b * 8 + h) * 64 + f) * 1024 + t] = pk2bf(acc[h][0], acc[h][1]);
    // transpose to xr_t via LDS
    #pragma unroll
    for (int h = 0; h < 8; h++) {
        tr[(tx * 2 + 0) * 72 + h * 8 + fy] = f2bf(acc[h][0]);
        tr[(tx * 2 + 1) * 72 + h * 8 + fy] = f2bf(acc[h][1]);
    }
    __syncthreads();
    int h2 = tid & 7, trow = tid >> 3;            // trow 0..31
    #pragma unroll
    for (int i = 0; i < 2; i++) {
        int t2 = trow + i * 32;
        i32x4 v = *(const i32x4*)&tr[t2 * 72 + h2 * 8];
        *(i32x4*)&xr_t[((size_t)b * 1024 + tb * 64 + t2) * 512 + h2 * 64 + fb * 8] = v;
    }
}

// ---------------------------------------------------------------------------
// Kernel 2: qk[D][t] = sum_c wqk_b[D][c] * xr[c][t]   (per batch)
// Tiles 64D x 64t, BK=64, grid (16 t, 16 D, 4 b) = 1024 blocks, 18.4KB LDS
// -> 4 blocks/CU. Store qk_t[b][h][t][d2] bf16, d2 = D&127.
// ---------------------------------------------------------------------------
__global__ __launch_bounds__(256, 4) void k_qk(
    const short* __restrict__ wqk_b, const short* __restrict__ xr_t,
    short* __restrict__ qk_t)
{
    __shared__ __align__(16) short As[64 * 72];   // [D-local][64 data + 8 pad]
    __shared__ __align__(16) short Bs[64 * 72];   // [t-local][64 data + 8 pad]
    int tid = threadIdx.x;
    int w = tid >> 6, lane = tid & 63;
    int quad = lane >> 4, l16 = lane & 15;
    int t0 = blockIdx.x * 64;
    int Dt = blockIdx.y;                          // D0 = Dt*64; h = Dt>>1
    int b  = blockIdx.z;

    f32x4 acc[4];
    #pragma unroll
    for (int tt = 0; tt < 4; tt++) acc[tt] = (f32x4){0.f,0.f,0.f,0.f};

    const short* Ag = wqk_b + (size_t)Dt * 64 * 512;
    const short* Bg = xr_t + ((size_t)b * 1024 + t0) * 512;

    int s_row = tid >> 2, s_col = (tid & 3) * 16;

    for (int kk = 0; kk < 512; kk += 64) {
        __syncthreads();
        #pragma unroll
        for (int i = 0; i < 2; i++) {
            *(i32x4*)&As[s_row * 72 + s_col + i * 8] =
                *(const i32x4*)&Ag[(size_t)s_row * 512 + kk + s_col + i * 8];
            *(i32x4*)&Bs[s_row * 72 + s_col + i * 8] =
                *(const i32x4*)&Bg[(size_t)s_row * 512 + kk + s_col + i * 8];
        }
        __syncthreads();
        bf16x8 af[2];
        #pragma unroll
        for (int kc = 0; kc < 2; kc++)
            af[kc] = *(const bf16x8*)&As[(w * 16 + l16) * 72 + kc * 32 + quad * 8];
        #pragma unroll
        for (int tt = 0; tt < 4; tt++) {
            bf16x8 bf0 = *(const bf16x8*)&Bs[(tt * 16 + l16) * 72 + quad * 8];
            bf16x8 bf1 = *(const bf16x8*)&Bs[(tt * 16 + l16) * 72 + 32 + quad * 8];
            acc[tt] = MFMA16(af[0], bf0, acc[tt]);
            acc[tt] = MFMA16(af[1], bf1, acc[tt]);
        }
    }
    int h = Dt >> 1;
    int d2 = (Dt & 1) * 64 + w * 16 + quad * 4;
    #pragma unroll
    for (int tt = 0; tt < 4; tt++) {
        bf16x4 pk;
        pk.x = f2bf(acc[tt][0]); pk.y = f2bf(acc[tt][1]);
        pk.z = f2bf(acc[tt][2]); pk.w = f2bf(acc[tt][3]);
        int t = t0 + tt * 16 + l16;
        *(bf16x4*)&qk_t[(((size_t)b * 8 + h) * 1024 + t) * 128 + d2] = pk;
    }
}

// ---------------------------------------------------------------------------
// Kernel 3: attention, barrier-free m-partitioned flash (no-max softmax).
// Grid (16 nb, 32 bh, 2 mh) = 1024 blocks. Each wave owns an m-slice of 32
// per 128-m tile; K/V frags read DIRECTLY from global (L2), zero LDS staging,
// zero barriers in the m-loop. P round-trips per-wave private LDS. Partial
// O[64n][64d] per wave, serial LDS reduce at the end. 43.5KB LDS, ~3 blk/CU.
// ---------------------------------------------------------------------------
__global__ __launch_bounds__(256, 3) void k_attn(
    const short* __restrict__ qk_t, const short* __restrict__ xi_v,
    const float* __restrict__ rel_bias, float* __restrict__ o_part,
    float* __restrict__ lsum)
{
    __shared__ __align__(16) short Ps[4][64 * 40];      // per-wave P^T [n][m32+pad]
    __shared__ __align__(16) short lut_rot[4][144 * 4]; // rotated bf16x4 exp-bias lut
    __shared__ __align__(16) float Or[64 * 68];         // O reduce [d][n+pad]; elut temp
    __shared__ float lsum_s[4][64];

    int tid = threadIdx.x;
    int w = tid >> 6, lane = tid & 63;
    int quad = lane >> 4, l16 = lane & 15;
    int nb = blockIdx.x, bh = blockIdx.y, mh = blockIdx.z;
    int h = bh & 7;
    int n_base = nb * 64;
    int base_rel = mh * 512 - n_base - 63;   // global rel for lut index 0

    // phase 1: exp2(bias*QSCALE) floats into Or[0..575] (rel range this block sees)
    for (int i = tid; i < 576; i += 256) {
        int rel = base_rel + i;
        int ret = (rel >= 0) ? 16 : 0;
        int na = rel < 0 ? -rel : rel;
        int idx;
        if (na < 8) idx = ret + na;
        else {
            int vl = 8 + (int)(log2f((float)na * 0.125f) * 2.0f);
            vl = vl > 15 ? 15 : vl;
            idx = ret + vl;
        }
        Or[i] = exp2f(rel_bias[idx * 8 + h] * QSCALE);
    }
    __syncthreads();
    // phase 2: 4-way rotated bf16 lut: lut_rot[r][4k..] = elut[4k+r .. 4k+r+3]
    for (int e = tid; e < 576; e += 256) {
        int r = e / 144, k = e - r * 144;
        int i0 = 4 * k + r;
        bf16x4 pk;
        pk.x = f2bf(Or[i0 > 575 ? 575 : i0]);
        pk.y = f2bf(Or[i0 + 1 > 575 ? 575 : i0 + 1]);
        pk.z = f2bf(Or[i0 + 2 > 575 ? 575 : i0 + 2]);
        pk.w = f2bf(Or[i0 + 3 > 575 ? 575 : i0 + 3]);
        *(bf16x4*)&lut_rot[r][k * 4] = pk;
    }
    __syncthreads();

    const short* qb = qk_t + (size_t)bh * (1024 * 128);
    const short* vb = xi_v + (size_t)bh * (64 * 1024);

    // Q B-frags for all 4 n-tiles, in registers for the whole kernel
    bf16x8 qf[4][2];
    #pragma unroll
    for (int nt = 0; nt < 4; nt++)
        #pragma unroll
        for (int kc = 0; kc < 2; kc++)
            qf[nt][kc] = *(const bf16x8*)&qb[(size_t)(n_base + nt * 16 + l16) * 128 + kc * 32 + quad * 8];

    f32x4 acc[4][4];                  // partial O tiles [nt][dt]
    #pragma unroll
    for (int nt = 0; nt < 4; nt++)
        #pragma unroll
        for (int dt = 0; dt < 4; dt++) acc[nt][dt] = (f32x4){0.f,0.f,0.f,0.f};
    f32x4 lp = (f32x4){0.f,0.f,0.f,0.f};   // l partials per nt

    short* psw = &Ps[w][0];

    #pragma unroll 1
    for (int it = 0; it < 4; it++) {
        int mloc  = it * 128 + w * 32;        // m-slice local to mh half
        int mbase = mh * 512 + mloc;          // global m of wave's 32-slice
        // V B-frags (k = this wave's 32 m) direct from global
        bf16x8 vf[4];
        #pragma unroll
        for (int dt = 0; dt < 4; dt++)
            vf[dt] = *(const bf16x8*)&vb[(size_t)(dt * 16 + l16) * 1024 + mbase + quad * 8];

        // QK^T + softmax + P pack, per 16-m subtile
        #pragma unroll
        for (int mt = 0; mt < 2; mt++) {
            bf16x8 kf0 = *(const bf16x8*)&qb[(size_t)(mbase + mt * 16 + l16) * 128 + 64 + quad * 8];
            bf16x8 kf1 = *(const bf16x8*)&qb[(size_t)(mbase + mt * 16 + l16) * 128 + 96 + quad * 8];
            #pragma unroll
            for (int nt = 0; nt < 4; nt++) {
                f32x4 s = (f32x4){0.f,0.f,0.f,0.f};
                s = MFMA16(kf0, qf[nt][0], s);
                s = MFMA16(kf1, qf[nt][1], s);
                // rel = m - n (+63 local offset); 4 regs = 4 consecutive rel
                int rel0 = mloc + mt * 16 + quad * 4 - (nt * 16 + l16) + 63;
                bf16x4 lv = *(const bf16x4*)&lut_rot[rel0 & 3][(rel0 >> 2) * 4];
                f32x4 p;
                p[0] = exp2f(s[0]) * bf2f(lv.x);
                p[1] = exp2f(s[1]) * bf2f(lv.y);
                p[2] = exp2f(s[2]) * bf2f(lv.z);
                p[3] = exp2f(s[3]) * bf2f(lv.w);
                lp[nt] += p[0] + p[1] + p[2] + p[3];
                bf16x4 pk;
                pk.x = f2bf(p[0]); pk.y = f2bf(p[1]);
                pk.z = f2bf(p[2]); pk.w = f2bf(p[3]);
                *(bf16x4*)&psw[(nt * 16 + l16) * 40 + mt * 16 + quad * 4] = pk;
            }
        }
        // PV over this wave's own 32-m slice (K=32), same-wave LDS ordering
        #pragma unroll
        for (int nt = 0; nt < 4; nt++) {
            bf16x8 pf = *(const bf16x8*)&psw[(nt * 16 + l16) * 40 + quad * 8];
            #pragma unroll
            for (int dt = 0; dt < 4; dt++)
                acc[nt][dt] = MFMA16(pf, vf[dt], acc[nt][dt]);
        }
    }

    // l: reduce across quads, stash per-wave rows
    #pragma unroll
    for (int nt = 0; nt < 4; nt++) {
        float v = lp[nt];
        v += __shfl_xor(v, 16);
        v += __shfl_xor(v, 32);
        if (quad == 0) lsum_s[w][nt * 16 + l16] = v;
    }
    __syncthreads();

    // serial cross-wave O reduction into Or[d][n]
    #pragma unroll 1
    for (int ww = 0; ww < 4; ww++) {
        if (w == ww) {
            #pragma unroll
            for (int nt = 0; nt < 4; nt++)
                #pragma unroll
                for (int dt = 0; dt < 4; dt++) {
                    float* dst = &Or[(dt * 16 + l16) * 68 + nt * 16 + quad * 4];
                    if (ww == 0) *(f32x4*)dst = acc[nt][dt];
                    else {
                        f32x4 old = *(const f32x4*)dst;
                        *(f32x4*)dst = old + acc[nt][dt];
                    }
                }
        }
        __syncthreads();
    }

    // store raw O partial: o_part[mh][bh][d][n] (coalesced f32x4)
    int d = tid >> 2, n0 = (tid & 3) * 16;
    float* op = &o_part[(((size_t)mh * 32 + bh) * 64 + d) * 1024 + n_base + n0];
    #pragma unroll
    for (int i = 0; i < 4; i++)
        *(f32x4*)&op[i * 4] = *(const f32x4*)&Or[d * 68 + n0 + i * 4];
    if (tid < 64) {
        float s = lsum_s[0][tid] + lsum_s[1][tid] + lsum_s[2][tid] + lsum_s[3][tid];
        lsum[((size_t)bh * 2 + mh) * 1024 + n_base + tid] = s;
    }
}

// ---------------------------------------------------------------------------
// Kernel 4: merge two m-halves (trivial: no max logic) + output projection
// out[b,c,f,t] = sum_h o[h] w_out[c,h]
// ---------------------------------------------------------------------------
__global__ __launch_bounds__(512) void k_proj_out(
    const float* __restrict__ o_part, const float* __restrict__ lsum,
    const float* __restrict__ w_out, float* __restrict__ out)
{
    __shared__ float w_s[512];
    __shared__ float o_s[8][64];
    int tid = threadIdx.x;
    int tx = tid & 63, ty = tid >> 6;
    int tb = blockIdx.x, f = blockIdx.y, b = blockIdx.z;
    w_s[tid] = w_out[tid];
    int t = tb * 64 + tx;
    int bh = b * 8 + ty;
    float l0 = lsum[((size_t)bh * 2 + 0) * 1024 + t];
    float l1 = lsum[((size_t)bh * 2 + 1) * 1024 + t];
    float o0 = o_part[((size_t)(0 * 32 + bh) * 64 + f) * 1024 + t];
    float o1 = o_part[((size_t)(1 * 32 + bh) * 64 + f) * 1024 + t];
    o_s[ty][tx] = (o0 + o1) / (l0 + l1);
    __syncthreads();
    float ov[8];
    #pragma unroll
    for (int hh = 0; hh < 8; hh++) ov[hh] = o_s[hh][tx];
    #pragma unroll
    for (int j = 0; j < 8; j++) {
        int c = ty * 8 + j;
        float a = 0.f;
        #pragma unroll
        for (int hh = 0; hh < 8; hh++) a = fmaf(ov[hh], w_s[c * 8 + hh], a);
        out[(((size_t)b * 64 + c) * 64 + f) * 1024 + t] = a;
    }
}

// ---------------------------------------------------------------------------
extern "C" void kernel_launch(void* const* d_in, const int* in_sizes, int n_in,
                              void* d_out, int out_size, void* d_ws, size_t ws_size,
                              hipStream_t stream)
{
    const float* x        = (const float*)d_in[0];   // [4][64][64][1024]
    const float* w_in     = (const float*)d_in[1];   // [8][64]
    const float* w_qk     = (const float*)d_in[2];   // [1024][512]
    const float* w_out    = (const float*)d_in[3];   // [64][8]
    const float* rel_bias = (const float*)d_in[4];   // [32][8]
    float* out = (float*)d_out;                      // [4][64][64][1024]

    char* ws = (char*)d_ws;                          // ~33.3 MB used
    short* wqk_b  = (short*)(ws);                    // 1 MB
    short* xi_v   = (short*)(ws + (size_t)1  * (1 << 20));  // 4 MB
    short* xr_t   = (short*)(ws + (size_t)5  * (1 << 20));  // 4 MB
    short* qk_t   = (short*)(ws + (size_t)9  * (1 << 20));  // 8 MB
    float* o_part = (float*)(ws + (size_t)17 * (1 << 20));  // 16 MB (2 halves)
    float* lsum   = (float*)(ws + (size_t)33 * (1 << 20));  // 0.25 MB

    hipLaunchKernelGGL(k_prep,     dim3(2048),       dim3(256), 0, stream, w_qk, wqk_b);
    hipLaunchKernelGGL(k_proj_in,  dim3(16, 8, 4),   dim3(256), 0, stream, x, w_in, xi_v, xr_t);
    hipLaunchKernelGGL(k_qk,       dim3(16, 16, 4),  dim3(256), 0, stream, wqk_b, xr_t, qk_t);
    hipLaunchKernelGGL(k_attn,     dim3(16, 32, 2),  dim3(256), 0, stream, qk_t, xi_v, rel_bias, o_part, lsum);
    hipLaunchKernelGGL(k_proj_out, dim3(16, 64, 4),  dim3(512), 0, stream, o_part, lsum, w_out, out);
}